// Round 3
// baseline (1213.402 us; speedup 1.0000x reference)
//
#include <hip/hip_runtime.h>
#include <hip/hip_bf16.h>
#include <math.h>

// Problem constants
namespace {
constexpr int Bn = 8;
constexpr int Hn = 16;
constexpr int Ln = 512;
constexpr int HD = 64;
constexpr int DM = 1024;
constexpr int TL = 1024;  // 2*L
constexpr size_t QS  = (size_t)Bn * Hn * Ln * HD;  // 4,194,304 floats per q/k/v
constexpr size_t FSz = (size_t)Hn * Ln * TL;       // 8,388,608 floats per-batch F (or G)
}

// ---------------------------------------------------------------------------
// K1: qkv = x @ Wqkv.  M=4096 (b*L), K=1024, N=3072. 128x128 tile, 8x8/thread.
// Output scattered directly into q/k/v arrays with layout [b][h][l][d].
// ---------------------------------------------------------------------------
__global__ __launch_bounds__(256) void qkv_gemm(const float* __restrict__ x,
                                                const float* __restrict__ W,
                                                float* __restrict__ qarr,
                                                float* __restrict__ karr,
                                                float* __restrict__ varr) {
  __shared__ float As[16][132];  // [k][m]
  __shared__ float Bs[16][132];  // [k][n]
  const int t = threadIdx.x;
  const int m0 = blockIdx.y * 128;
  const int n0 = blockIdx.x * 128;
  const int tr = t >> 4, tc = t & 15;
  float acc[8][8];
#pragma unroll
  for (int i = 0; i < 8; ++i)
#pragma unroll
    for (int j = 0; j < 8; ++j) acc[i][j] = 0.f;

  for (int k0 = 0; k0 < 1024; k0 += 16) {
#pragma unroll
    for (int i = 0; i < 2; ++i) {
      int idx = t + i * 256;              // 0..511 float4s of A tile (128x16)
      int r = idx >> 2;                   // row 0..127
      int c4 = (idx & 3) * 4;             // k col 0,4,8,12
      float4 av = *(const float4*)(x + (size_t)(m0 + r) * 1024 + k0 + c4);
      As[c4 + 0][r] = av.x; As[c4 + 1][r] = av.y;
      As[c4 + 2][r] = av.z; As[c4 + 3][r] = av.w;
    }
#pragma unroll
    for (int i = 0; i < 2; ++i) {
      int idx = t + i * 256;              // 0..511 float4s of B tile (16x128)
      int r = idx >> 5;                   // k row 0..15
      int c4 = (idx & 31) * 4;            // n col
      *(float4*)(&Bs[r][c4]) = *(const float4*)(W + (size_t)(k0 + r) * 3072 + n0 + c4);
    }
    __syncthreads();
#pragma unroll
    for (int kk = 0; kk < 16; ++kk) {
      float a[8], b[8];
      *(float4*)(a)     = *(const float4*)(&As[kk][tr * 8]);
      *(float4*)(a + 4) = *(const float4*)(&As[kk][tr * 8 + 4]);
      *(float4*)(b)     = *(const float4*)(&Bs[kk][tc * 8]);
      *(float4*)(b + 4) = *(const float4*)(&Bs[kk][tc * 8 + 4]);
#pragma unroll
      for (int i = 0; i < 8; ++i)
#pragma unroll
        for (int j = 0; j < 8; ++j) acc[i][j] = fmaf(a[i], b[j], acc[i][j]);
    }
    __syncthreads();
  }
  const int part = n0 >> 10;
  float* dst = (part == 0) ? qarr : (part == 1 ? karr : varr);
  const int nbase = n0 & 1023;
#pragma unroll
  for (int i = 0; i < 8; ++i) {
    int m = m0 + tr * 8 + i;
    int bb = m >> 9, l = m & 511;
#pragma unroll
    for (int j = 0; j < 8; ++j) {
      int n = nbase + tc * 8 + j;
      int h = n >> 6, d = n & 63;
      dst[(((size_t)(bb * Hn + h) * Ln + l) << 6) + d] = acc[i][j];
    }
  }
}

// ---------------------------------------------------------------------------
// K2 (per batch): F[h] = (q[b,h]+r_w_bias[h]) @ R ; G[h] = k[b,h] @ R
// Per (h,which): (512x64)@(64x1024). Tile 64x64, K=64, 4x4/thread.
// ---------------------------------------------------------------------------
__global__ __launch_bounds__(256) void fg_gemm(const float* __restrict__ qarr,
                                               const float* __restrict__ karr,
                                               const float* __restrict__ rwb,
                                               const float* __restrict__ R,
                                               float* __restrict__ F,
                                               float* __restrict__ G,
                                               int b) {
  __shared__ float As[64][68];  // [k(d)][m]
  __shared__ float Rs[64][68];  // [k(d)][n]
  const int t = threadIdx.x;
  const int h = blockIdx.z >> 1;
  const int which = blockIdx.z & 1;  // 0 = F (q + r_w_bias), 1 = G (k)
  const int m0 = blockIdx.y * 64;
  const int n0 = blockIdx.x * 64;
  const float* A = (which == 0 ? qarr : karr) + (size_t)(b * Hn + h) * Ln * HD;

#pragma unroll
  for (int i = 0; i < 4; ++i) {
    int idx = t + i * 256;              // 0..1023
    int r = idx >> 4;                   // 0..63
    int c4 = (idx & 15) * 4;            // 0..60
    float4 av = *(const float4*)(A + (size_t)(m0 + r) * HD + c4);
    if (which == 0) {
      float4 bv = *(const float4*)(rwb + h * HD + c4);
      av.x += bv.x; av.y += bv.y; av.z += bv.z; av.w += bv.w;
    }
    As[c4 + 0][r] = av.x; As[c4 + 1][r] = av.y;
    As[c4 + 2][r] = av.z; As[c4 + 3][r] = av.w;
    *(float4*)(&Rs[r][c4]) = *(const float4*)(R + (size_t)r * TL + n0 + c4);
  }
  __syncthreads();
  const int tr = t >> 4, tc = t & 15;
  float acc[4][4];
#pragma unroll
  for (int i = 0; i < 4; ++i)
#pragma unroll
    for (int j = 0; j < 4; ++j) acc[i][j] = 0.f;
#pragma unroll 16
  for (int kk = 0; kk < 64; ++kk) {
    float a[4], bb[4];
    *(float4*)(a)  = *(const float4*)(&As[kk][tr * 4]);
    *(float4*)(bb) = *(const float4*)(&Rs[kk][tc * 4]);
#pragma unroll
    for (int i = 0; i < 4; ++i)
#pragma unroll
      for (int j = 0; j < 4; ++j) acc[i][j] = fmaf(a[i], bb[j], acc[i][j]);
  }
  float* O = (which == 0 ? F : G) + ((size_t)h * Ln + m0) * TL + n0;
#pragma unroll
  for (int i = 0; i < 4; ++i) {
    float4 v = make_float4(acc[i][0], acc[i][1], acc[i][2], acc[i][3]);
    *(float4*)(O + (size_t)(tr * 4 + i) * TL + tc * 4) = v;
  }
}

// ---------------------------------------------------------------------------
// K3 (per batch): fused scores + prev_out write + online softmax + P@V.
// Block: 16 q-rows of one (b,h); iterates 8 j-tiles of 64.
//   score[q,j] = ((q+r_r)·k[j] + F[q,512+j-q] + G[j,512+q-j]) / 8 + skip*prev
// ---------------------------------------------------------------------------
__global__ __launch_bounds__(256) void attn_fused(const float* __restrict__ qarr,
                                                  const float* __restrict__ karr,
                                                  const float* __restrict__ varr,
                                                  const float* __restrict__ rrb,
                                                  const float* __restrict__ F,
                                                  const float* __restrict__ G,
                                                  const float* __restrict__ prev,
                                                  const int* __restrict__ skip,
                                                  float* __restrict__ out,
                                                  float* __restrict__ pout,
                                                  int b) {
  __shared__ float qrT[64][18];   // [d][q]
  __shared__ float ktT[64][68];   // [d][j]
  __shared__ float vt[64][68];    // [j][d]
  __shared__ float St[16][68];    // scores then P
  __shared__ float red[16][16];
  __shared__ float mrun[16], lrun[16], mnew_s[16], alpha_s[16];

  const int t = threadIdx.x;
  const int h = blockIdx.y;
  const int q0 = blockIdx.x * 16;
  const float pf = (skip[0] != 0) ? 1.f : 0.f;
  const size_t bh = (size_t)(b * Hn + h);

  // stage qrT = q + r_r_bias, transposed [d][q]
  {
    int r = t >> 4, c4 = (t & 15) * 4;
    float4 av = *(const float4*)(qarr + (bh * Ln + q0 + r) * HD + c4);
    float4 bv = *(const float4*)(rrb + h * HD + c4);
    qrT[c4 + 0][r] = av.x + bv.x; qrT[c4 + 1][r] = av.y + bv.y;
    qrT[c4 + 2][r] = av.z + bv.z; qrT[c4 + 3][r] = av.w + bv.w;
  }
  if (t < 16) { mrun[t] = -INFINITY; lrun[t] = 0.f; }

  const int tq = t >> 4, tj = t & 15;  // score mapping: row tq, cols tj*4..+3
  const int d = t & 63, qg = t >> 6;   // PV mapping: col d, rows qg*4..+3
  float O[4] = {0.f, 0.f, 0.f, 0.f};

  for (int jt = 0; jt < 8; ++jt) {
    const int j0 = jt * 64;
    __syncthreads();  // protect previous tile's LDS (and qrT staging, iter 0)
#pragma unroll
    for (int i = 0; i < 4; ++i) {
      int idx = t + i * 256;
      int r = idx >> 4, c4 = (idx & 15) * 4;
      float4 kv = *(const float4*)(karr + (bh * Ln + j0 + r) * HD + c4);
      ktT[c4 + 0][r] = kv.x; ktT[c4 + 1][r] = kv.y;
      ktT[c4 + 2][r] = kv.z; ktT[c4 + 3][r] = kv.w;
      *(float4*)(&vt[r][c4]) = *(const float4*)(varr + (bh * Ln + j0 + r) * HD + c4);
    }
    __syncthreads();

    // AC partial: s[ji] = sum_d qr[tq][d]*k[tj*4+ji][d]
    float s[4] = {0.f, 0.f, 0.f, 0.f};
#pragma unroll 8
    for (int dd = 0; dd < 64; ++dd) {
      float a = qrT[dd][tq];
      float4 bv = *(const float4*)(&ktT[dd][tj * 4]);
      s[0] = fmaf(a, bv.x, s[0]);
      s[1] = fmaf(a, bv.y, s[1]);
      s[2] = fmaf(a, bv.z, s[2]);
      s[3] = fmaf(a, bv.w, s[3]);
    }
    // add F/G/prev, write prev_out (4 consecutive floats per thread)
    {
      const int q = q0 + tq;
      const size_t pbase = ((bh * Ln + q) << 9) + j0 + tj * 4;
      float4 pv4 = *(const float4*)(prev + pbase);
      const float pin[4] = {pv4.x, pv4.y, pv4.z, pv4.w};
      float4 o4;
      float* o4p = &o4.x;
#pragma unroll
      for (int ji = 0; ji < 4; ++ji) {
        const int j = j0 + tj * 4 + ji;
        float fv = F[((size_t)h * Ln + q) * TL + (Ln + j - q)];
        float gv = G[((size_t)h * Ln + j) * TL + (Ln + q - j)];
        float sc = (s[ji] + fv + gv) * 0.125f + pf * pin[ji];
        o4p[ji] = sc;
        s[ji] = sc;
        St[tq][tj * 4 + ji] = sc;
      }
      *(float4*)(pout + pbase) = o4;
    }
    __syncthreads();
    // tile row max
    {
      const int r = t >> 4, seg = t & 15;
      float mx = St[r][seg * 4];
#pragma unroll
      for (int u = 1; u < 4; ++u) mx = fmaxf(mx, St[r][seg * 4 + u]);
      red[r][seg] = mx;
    }
    __syncthreads();
    if (t < 16) {
      float mx = red[t][0];
#pragma unroll
      for (int u = 1; u < 16; ++u) mx = fmaxf(mx, red[t][u]);
      float mn = fmaxf(mrun[t], mx);
      alpha_s[t] = __expf(mrun[t] - mn);
      mnew_s[t] = mn;
      mrun[t] = mn;
    }
    __syncthreads();
    // P = exp(s - m_new)
    {
      const float mn = mnew_s[tq];
#pragma unroll
      for (int ji = 0; ji < 4; ++ji) St[tq][tj * 4 + ji] = __expf(s[ji] - mn);
    }
    __syncthreads();
    // tile row sum
    {
      const int r = t >> 4, seg = t & 15;
      float sm = 0.f;
#pragma unroll
      for (int u = 0; u < 4; ++u) sm += St[r][seg * 4 + u];
      red[r][seg] = sm;
    }
    __syncthreads();
    if (t < 16) {
      float sm = 0.f;
#pragma unroll
      for (int u = 0; u < 16; ++u) sm += red[t][u];
      lrun[t] = lrun[t] * alpha_s[t] + sm;
    }
    // O rescale + accumulate P@V
#pragma unroll
    for (int i = 0; i < 4; ++i) O[i] *= alpha_s[qg * 4 + i];
#pragma unroll 8
    for (int j = 0; j < 64; ++j) {
      float vv = vt[j][d];
#pragma unroll
      for (int i = 0; i < 4; ++i) O[i] = fmaf(St[qg * 4 + i][j], vv, O[i]);
    }
  }
  __syncthreads();
#pragma unroll
  for (int i = 0; i < 4; ++i) {
    int lq = qg * 4 + i;
    float val = O[i] / lrun[lq];
    out[((size_t)b * Ln + q0 + lq) * DM + h * HD + d] = val;
  }
}

// ---------------------------------------------------------------------------
// kernel_launch
// d_in (fp32 per reference): x, prev, Wqkv, r_r_bias, r_w_bias, rel_pos,
//                            skip_op(int)
// d_out (fp32): out (8*512*1024) then prev_out (8*16*512*512)
// ws layout (fp32): q | k | v | F_batch | G_batch   (= 117.4 MB)
// ---------------------------------------------------------------------------
extern "C" void kernel_launch(void* const* d_in, const int* in_sizes, int n_in,
                              void* d_out, int out_size, void* d_ws, size_t ws_size,
                              hipStream_t stream) {
  const float* x    = (const float*)d_in[0];
  const float* prev = (const float*)d_in[1];
  const float* W    = (const float*)d_in[2];
  const float* rrb  = (const float*)d_in[3];
  const float* rwb  = (const float*)d_in[4];
  const float* R    = (const float*)d_in[5];
  const int*   skip = (const int*)d_in[6];

  float* out  = (float*)d_out;
  float* pout = out + (size_t)Bn * Ln * DM;

  float* ws = (float*)d_ws;
  float* qarr = ws;
  float* karr = ws + QS;
  float* varr = ws + 2 * QS;
  float* Farr = ws + 3 * QS;
  float* Garr = Farr + FSz;

  qkv_gemm<<<dim3(3072 / 128, 4096 / 128), 256, 0, stream>>>(x, W, qarr, karr, varr);
  for (int b = 0; b < Bn; ++b) {
    fg_gemm<<<dim3(TL / 64, Ln / 64, Hn * 2), 256, 0, stream>>>(qarr, karr, rwb, R, Farr, Garr, b);
    attn_fused<<<dim3(Ln / 16, Hn), 256, 0, stream>>>(qarr, karr, varr, rrb, Farr, Garr,
                                                      prev, skip, out, pout, b);
  }
}